// Round 1
// baseline (586.691 us; speedup 1.0000x reference)
//
#include <hip/hip_runtime.h>

// Fused attention layer for B=8, CH=64, D=32, H=W=64, S=32.
// Key reduction: output = mean_d(x + f*o) only needs Abar = mean_j A[:,j],
// Obar = V*Abar, res[c] = Xbar[c] + f*(bo[c] + Wo*Obar).  Full o/out never
// materialized.
//
// One block = (b, h, tile of 8 w).  256 threads = 4 waves.
// LDS: X tile bf16 [c][w'][d_pad36] (36KB), reused for K|Q bf16 after
// projections; weights bf16 (padded rows, ~17KB); small f32 scratch.
// Total ~60KB -> 2 blocks/CU.

namespace {
constexpr int kB = 8, kC = 64, kD = 32, kH = 64, kW = 64, kS = 32;
constexpr int TW = 8;     // w positions per block
constexpr int NT = 256;   // threads per block
constexpr int RP = 36;    // padded bf16 row length for X/K/Q (d dim 32 -> 36)
constexpr int WPAD = 66;  // padded weight row (C=64 -> 66)
constexpr int OPAD = 34;  // padded Wo row (S=32 -> 34)

typedef unsigned short u16t;
typedef unsigned int u32t;

__device__ __forceinline__ float b2f(u16t u) {
    union { u32t i; float f; } v; v.i = ((u32t)u) << 16; return v.f;
}
__device__ __forceinline__ u16t f2b(float f) {
    union { u32t i; float f; } v; v.f = f;
    u32t r = v.i + 0x7FFFu + ((v.i >> 16) & 1u);  // round-nearest-even
    return (u16t)(r >> 16);
}
} // namespace

__global__ __launch_bounds__(NT) void attn_fused(
    const float* __restrict__ x,
    const float* __restrict__ Wk, const float* __restrict__ bk,
    const float* __restrict__ Wq, const float* __restrict__ bq,
    const float* __restrict__ Wv, const float* __restrict__ bv,
    const float* __restrict__ Wo, const float* __restrict__ bo,
    const float* __restrict__ factor,
    float* __restrict__ out)
{
    __shared__ u16t Wks[kS * WPAD], Wqs[kS * WPAD], Wvs[kS * WPAD];
    __shared__ u16t Wos[kC * OPAD];
    __shared__ float bks[kS], bqs[kS], bvs[kS], bos[kC];
    __shared__ u16t XKQ[kC * TW * RP];           // X[c][w'][36]; later K|Q
    __shared__ float Xbar[kC][TW];
    __shared__ float Apart[4][kD][TW];
    __shared__ float Obar[kS][TW];

    const int t  = threadIdx.x;
    const int wl = t & (TW - 1);   // w' 0..7
    const int r  = t >> 3;         // 0..31: s for proj, j for scores
    const int blk = blockIdx.x;    // b*512 + h*8 + wt
    const int wt = blk & 7;
    const int h  = (blk >> 3) & 63;
    const int b  = blk >> 9;
    const int w0 = wt * TW;

    // ---- stage weights (bf16) + biases (f32) ----
    #pragma unroll
    for (int k = 0; k < 8; ++k) {
        int e = k * NT + t;        // 0..2047
        int s = e >> 6, c = e & 63;
        Wks[s * WPAD + c] = f2b(Wk[e]);
        Wqs[s * WPAD + c] = f2b(Wq[e]);
        Wvs[s * WPAD + c] = f2b(Wv[e]);
        int co = e >> 5, so = e & 31;
        Wos[co * OPAD + so] = f2b(Wo[e]);
    }
    if (t < kS) { bks[t] = bk[t]; bqs[t] = bq[t]; bvs[t] = bv[t]; }
    if (t < kC) bos[t] = bo[t];

    // ---- stage X tile: x[b, c, d=r, h, w0+wl] -> XKQ[c][wl][d] bf16 ----
    {
        const int base0 = (b * kC * kD) * (kH * kW) + h * kW + w0 + wl;
        #pragma unroll 8
        for (int c = 0; c < kC; ++c) {
            float xv = x[base0 + (c * kD + r) * (kH * kW)];
            XKQ[(c * TW + wl) * RP + r] = f2b(xv);
        }
    }
    __syncthreads();

    // ---- Xbar[c][wl] = mean_d X ----
    #pragma unroll
    for (int half = 0; half < 2; ++half) {
        int c = r + half * 32;
        const u16t* row = &XKQ[(c * TW + wl) * RP];
        float s = 0.f;
        #pragma unroll
        for (int d = 0; d < kD; ++d) s += b2f(row[d]);
        Xbar[c][wl] = s * (1.0f / kD);
    }

    // ---- projections: thread (s=r, wl) computes K/Q/V[s][0..31] ----
    float accK[kD], accQ[kD], accV[kD];
    {
        float bkv = bks[r], bqv = bqs[r], bvv = bvs[r];
        #pragma unroll
        for (int i = 0; i < kD; ++i) { accK[i] = bkv; accQ[i] = bqv; accV[i] = bvv; }
    }
    #pragma unroll 2
    for (int c = 0; c < kC; ++c) {
        float wk = b2f(Wks[r * WPAD + c]);
        float wq = b2f(Wqs[r * WPAD + c]);
        float wv = b2f(Wvs[r * WPAD + c]);
        const ushort4* row = (const ushort4*)&XKQ[(c * TW + wl) * RP];
        #pragma unroll
        for (int ii = 0; ii < 8; ++ii) {
            ushort4 x4 = row[ii];
            float x0 = b2f(x4.x), x1 = b2f(x4.y), x2 = b2f(x4.z), x3 = b2f(x4.w);
            int i = ii * 4;
            accK[i+0] += wk * x0; accQ[i+0] += wq * x0; accV[i+0] += wv * x0;
            accK[i+1] += wk * x1; accQ[i+1] += wq * x1; accV[i+1] += wv * x1;
            accK[i+2] += wk * x2; accQ[i+2] += wq * x2; accV[i+2] += wv * x2;
            accK[i+3] += wk * x3; accQ[i+3] += wq * x3; accV[i+3] += wv * x3;
        }
    }
    __syncthreads();   // everyone done reading X tile

    // ---- write K,Q bf16 into XKQ (K at 0, Q at kS*TW*RP); V stays in regs ----
    {
        u16t* Kp = XKQ;
        u16t* Qp = XKQ + kS * TW * RP;
        int o = (r * TW + wl) * RP;
        #pragma unroll
        for (int i = 0; i < kD; ++i) { Kp[o + i] = f2b(accK[i]); Qp[o + i] = f2b(accQ[i]); }
    }
    __syncthreads();

    // ---- scores column j=r: a[i] = sum_s K[s][i]*Q[s][j]; softmax over i ----
    float a[kD];
    #pragma unroll
    for (int i = 0; i < kD; ++i) a[i] = 0.f;
    {
        const u16t* Kp = XKQ;
        const u16t* Qp = XKQ + kS * TW * RP;
        #pragma unroll 4
        for (int s2 = 0; s2 < kS; ++s2) {
            float qv = b2f(Qp[(s2 * TW + wl) * RP + r]);
            const ushort4* krow = (const ushort4*)&Kp[(s2 * TW + wl) * RP];
            #pragma unroll
            for (int ii = 0; ii < 8; ++ii) {
                ushort4 k4 = krow[ii];
                int i = ii * 4;
                a[i+0] += b2f(k4.x) * qv;
                a[i+1] += b2f(k4.y) * qv;
                a[i+2] += b2f(k4.z) * qv;
                a[i+3] += b2f(k4.w) * qv;
            }
        }
    }
    {
        const float scale = 0.17677669529663687f;  // 1/sqrt(32)
        float m = a[0];
        #pragma unroll
        for (int i = 1; i < kD; ++i) m = fmaxf(m, a[i]);
        float sum = 0.f;
        #pragma unroll
        for (int i = 0; i < kD; ++i) { a[i] = __expf((a[i] - m) * scale); sum += a[i]; }
        float inv = 1.0f / sum;
        #pragma unroll
        for (int i = 0; i < kD; ++i) a[i] *= inv;
    }

    // ---- Abar partials: butterfly over j within wave (lane bits 3..5) ----
    #pragma unroll
    for (int i = 0; i < kD; ++i) {
        float v = a[i];
        v += __shfl_xor(v, 8);
        v += __shfl_xor(v, 16);
        v += __shfl_xor(v, 32);
        a[i] = v;
    }
    if (((t >> 3) & 7) == 0) {             // one j-lane group per wave
        int wv = t >> 6;
        #pragma unroll
        for (int i = 0; i < kD; ++i) Apart[wv][i][wl] = a[i];
    }
    __syncthreads();

    // ---- Obar[s=r][wl] = (1/32) * sum_d V[s][d] * Abar[d] ----
    {
        float ob = 0.f;
        #pragma unroll
        for (int d = 0; d < kD; ++d) {
            float ab = Apart[0][d][wl] + Apart[1][d][wl]
                     + Apart[2][d][wl] + Apart[3][d][wl];
            ob += accV[d] * ab;
        }
        Obar[r][wl] = ob * (1.0f / kD);
    }
    __syncthreads();

    // ---- final: res[c] = Xbar[c] + f*(bo[c] + sum_s Wo[c][s]*Obar[s]) ----
    {
        const float fac = factor[0];
        #pragma unroll
        for (int half = 0; half < 2; ++half) {
            int c = r + half * 32;
            float acc = 0.f;
            #pragma unroll
            for (int s2 = 0; s2 < kS; ++s2)
                acc += b2f(Wos[c * OPAD + s2]) * Obar[s2][wl];
            float res = Xbar[c][wl] + fac * (bos[c] + acc);
            out[((b * kC + c) * kH + h) * kW + w0 + wl] = res;
        }
    }
}

extern "C" void kernel_launch(void* const* d_in, const int* in_sizes, int n_in,
                              void* d_out, int out_size, void* d_ws, size_t ws_size,
                              hipStream_t stream) {
    const float* x      = (const float*)d_in[0];
    const float* Wk     = (const float*)d_in[1];
    const float* bk     = (const float*)d_in[2];
    const float* Wq     = (const float*)d_in[3];
    const float* bq     = (const float*)d_in[4];
    const float* Wv     = (const float*)d_in[5];
    const float* bv     = (const float*)d_in[6];
    const float* Wo     = (const float*)d_in[7];
    const float* bo     = (const float*)d_in[8];
    const float* factor = (const float*)d_in[9];
    float* out = (float*)d_out;

    dim3 grid(kB * kH * (kW / TW));  // 4096 blocks
    attn_fused<<<grid, NT, 0, stream>>>(x, Wk, bk, Wq, bq, Wv, bv, Wo, bo, factor, out);
}

// Round 3
// 449.695 us; speedup vs baseline: 1.3046x; 1.3046x over previous
//
#include <hip/hip_runtime.h>

// R3: MFMA version, LDS trimmed under the 64 KiB/workgroup static limit
// (R2 aborted at 78.5 KB static LDS).  Weight matrices are no longer staged
// in LDS: Wk/Wq/Wv A-fragments and Wo rows are read directly from global
// (8 KB total, L1/L2-resident, identical across all blocks).
//
// Math: out = mean_d(x + f*o) = Xbar + f*(bo + Wo*(V*Abar)),
//       Abar = mean_j softmax_i(K^T Q / sqrt(S))[i,j].
// Per block (b, h, 8 w): X staged bf16 in MFMA-B layout [n=(w',d)][c]
// (144 B rows); proj K,Q,V via mfma_f32_16x16x32_bf16; K|Q written back into
// the X region (K at ushort [0,32), Q at [40,72) per row; each wave owns its
// own 64-row slice, scores read the same slice); V to VT[n][s].

namespace {
constexpr int kB = 8, kC = 64, kD = 32, kH = 64, kW = 64, kS = 32;
constexpr int TW = 8, NT = 256;
constexpr int XR = 72;    // KQX row length in ushorts (144 B)
constexpr int VR = 36;    // VT row length in ushorts (72 B)
constexpr int QOFF = 40;  // Q offset (ushorts) within a KQX row (byte 80)

typedef unsigned short u16t;
typedef unsigned int u32t;
typedef __attribute__((ext_vector_type(8))) short bf16x8;
typedef __attribute__((ext_vector_type(4))) float f32x4;
typedef __attribute__((ext_vector_type(4))) short short4v;

__device__ __forceinline__ float b2f(u16t u) {
    union { u32t i; float f; } v; v.i = ((u32t)u) << 16; return v.f;
}
__device__ __forceinline__ u16t f2b(float f) {
    union { u32t i; float f; } v; v.f = f;
    u32t r = v.i + 0x7FFFu + ((v.i >> 16) & 1u);  // RNE
    return (u16t)(r >> 16);
}
__device__ __forceinline__ bf16x8 pack8(const float4 f0, const float4 f1) {
    bf16x8 a;
    a[0] = (short)f2b(f0.x); a[1] = (short)f2b(f0.y);
    a[2] = (short)f2b(f0.z); a[3] = (short)f2b(f0.w);
    a[4] = (short)f2b(f1.x); a[5] = (short)f2b(f1.y);
    a[6] = (short)f2b(f1.z); a[7] = (short)f2b(f1.w);
    return a;
}
} // namespace

__global__ __launch_bounds__(NT, 2) void attn_fused(
    const float* __restrict__ x,
    const float* __restrict__ Wk, const float* __restrict__ bk,
    const float* __restrict__ Wq, const float* __restrict__ bq,
    const float* __restrict__ Wv, const float* __restrict__ bv,
    const float* __restrict__ Wo, const float* __restrict__ bo,
    const float* __restrict__ factor,
    float* __restrict__ out)
{
    __shared__ u16t KQX[256 * XR];      // 36,864 B : X tile, then K|Q per row
    __shared__ u16t VT[256 * VR];       // 18,432 B : V[s,n] as VT[n][s]
    __shared__ float biasS[160];        //     640 B : bk|bq|bv|bo
    __shared__ float XbarS[kC * TW];    //   2,048 B
    __shared__ float AbarS[TW * 33];    //   1,056 B
    __shared__ float ObarS[TW * 33];    //   1,056 B   => total 60,096 B
    const int t = threadIdx.x;
    const int lane = t & 63;
    const int wv = t >> 6;
    const int l15 = lane & 15;
    const int quad = lane >> 4;

    // block swizzle: 8 w-tile siblings of one (b,h) row share blk%8 -> same XCD.
    const int blk = blockIdx.x;
    const int bh = (blk & 7) | ((blk >> 6) << 3);   // 0..511
    const int wt = (blk >> 3) & 7;
    const int b = bh >> 6, h = bh & 63, w0 = wt * TW;

    if (t < 32) { biasS[t] = bk[t]; biasS[32 + t] = bq[t]; biasS[64 + t] = bv[t]; }
    if (t < 64) { biasS[96 + t] = bo[t]; }

    // ---- stage X -> KQX[n][c] bf16, n = w'*32 + d ----
    {
        const float* xb = x + (size_t)(b * kC * kD) * (kH * kW) + h * kW + w0;
        u32t* dst = (u32t*)KQX;
        #pragma unroll
        for (int it = 0; it < 8; ++it) {
            int unit = it * NT + t;              // 0..2047
            int w4 = unit & 1;                   // which float4 of the 8-w tile
            int d  = (unit >> 1) & 31;
            int cp = unit >> 6;                  // c-pair 0..31
            int c  = cp * 2;
            const float4 fa = *(const float4*)(xb + (size_t)(c * kD + d) * (kH * kW) + w4 * 4);
            const float4 fb = *(const float4*)(xb + (size_t)((c + 1) * kD + d) * (kH * kW) + w4 * 4);
            int r0 = (w4 * 4) * kD + d;
            dst[(r0 + 0 * kD) * 36 + cp] = (u32t)f2b(fa.x) | ((u32t)f2b(fb.x) << 16);
            dst[(r0 + 1 * kD) * 36 + cp] = (u32t)f2b(fa.y) | ((u32t)f2b(fb.y) << 16);
            dst[(r0 + 2 * kD) * 36 + cp] = (u32t)f2b(fa.z) | ((u32t)f2b(fb.z) << 16);
            dst[(r0 + 3 * kD) * 36 + cp] = (u32t)f2b(fa.w) | ((u32t)f2b(fb.w) << 16);
        }
    }
    __syncthreads();

    // ---- Xbar[c][w'] = mean_d X  (before K/Q overwrite) ----
    {
        int c = t & 63, wb = t >> 6;
        #pragma unroll
        for (int half = 0; half < 2; ++half) {
            int wp = wb + half * 4;
            const u16t* col = &KQX[(wp * kD) * XR + c];
            float s = 0.f;
            #pragma unroll
            for (int d = 0; d < kD; ++d) s += b2f(col[d * XR]);
            XbarS[c * TW + wp] = s * (1.0f / kD);
        }
    }
    __syncthreads();   // all X reads done before any K/Q write

    // ---- projections via MFMA: wave wv owns n-rows [64*wv, 64*wv+64) ----
    {
        bf16x8 Bf[4][2];
        #pragma unroll
        for (int nt = 0; nt < 4; ++nt) {
            int row = wv * 64 + nt * 16 + l15;
            #pragma unroll
            for (int ks = 0; ks < 2; ++ks)
                Bf[nt][ks] = *(const bf16x8*)&KQX[row * XR + ks * 32 + quad * 8];
        }
        #pragma unroll
        for (int p = 0; p < 3; ++p) {
            const float* Wp = (p == 0) ? Wk : (p == 1) ? Wq : Wv;
            bf16x8 Af[2][2];
            #pragma unroll
            for (int m0 = 0; m0 < 2; ++m0)
                #pragma unroll
                for (int ks = 0; ks < 2; ++ks) {
                    const float* src = Wp + (m0 * 16 + l15) * kC + ks * 32 + quad * 8;
                    Af[m0][ks] = pack8(*(const float4*)src, *(const float4*)(src + 4));
                }
            float bvv[2][4];
            #pragma unroll
            for (int m0 = 0; m0 < 2; ++m0)
                #pragma unroll
                for (int r2 = 0; r2 < 4; ++r2)
                    bvv[m0][r2] = biasS[p * 32 + m0 * 16 + quad * 4 + r2];
            #pragma unroll
            for (int m0 = 0; m0 < 2; ++m0) {
                #pragma unroll
                for (int nt = 0; nt < 4; ++nt) {
                    f32x4 acc = {0.f, 0.f, 0.f, 0.f};
                    acc = __builtin_amdgcn_mfma_f32_16x16x32_bf16(Af[m0][0], Bf[nt][0], acc, 0, 0, 0);
                    acc = __builtin_amdgcn_mfma_f32_16x16x32_bf16(Af[m0][1], Bf[nt][1], acc, 0, 0, 0);
                    int row = wv * 64 + nt * 16 + l15;
                    short4v pk;
                    pk.x = (short)f2b(acc[0] + bvv[m0][0]);
                    pk.y = (short)f2b(acc[1] + bvv[m0][1]);
                    pk.z = (short)f2b(acc[2] + bvv[m0][2]);
                    pk.w = (short)f2b(acc[3] + bvv[m0][3]);
                    if (p < 2) {
                        *(short4v*)&KQX[row * XR + (p == 0 ? 0 : QOFF) + m0 * 16 + quad * 4] = pk;
                    } else {
                        *(short4v*)&VT[row * VR + m0 * 16 + quad * 4] = pk;
                    }
                }
            }
        }
    }
    __syncthreads();

    // ---- scores + softmax + Abar, 2 sites per wave (wave's own rows) ----
    {
        const float scale = 0.17677669529663687f;  // 1/sqrt(32)
        #pragma unroll
        for (int si = 0; si < 2; ++si) {
            int wp = wv * 2 + si;                  // site (w') 0..7
            bf16x8 Ka[2], Qb[2];
            #pragma unroll
            for (int m0 = 0; m0 < 2; ++m0)
                Ka[m0] = *(const bf16x8*)&KQX[(wp * kD + m0 * 16 + l15) * XR + quad * 8];
            #pragma unroll
            for (int n0 = 0; n0 < 2; ++n0)
                Qb[n0] = *(const bf16x8*)&KQX[(wp * kD + n0 * 16 + l15) * XR + QOFF + quad * 8];
            f32x4 sc[2][2];
            #pragma unroll
            for (int m0 = 0; m0 < 2; ++m0)
                #pragma unroll
                for (int n0 = 0; n0 < 2; ++n0) {
                    f32x4 z = {0.f, 0.f, 0.f, 0.f};
                    sc[m0][n0] = __builtin_amdgcn_mfma_f32_16x16x32_bf16(Ka[m0], Qb[n0], z, 0, 0, 0);
                }
            // softmax over i (rows) per column j = n0*16 + l15
            #pragma unroll
            for (int n0 = 0; n0 < 2; ++n0) {
                float m = sc[0][n0][0];
                #pragma unroll
                for (int m0 = 0; m0 < 2; ++m0)
                    #pragma unroll
                    for (int r2 = 0; r2 < 4; ++r2) m = fmaxf(m, sc[m0][n0][r2]);
                m = fmaxf(m, __shfl_xor(m, 16));
                m = fmaxf(m, __shfl_xor(m, 32));
                float sum = 0.f;
                #pragma unroll
                for (int m0 = 0; m0 < 2; ++m0)
                    #pragma unroll
                    for (int r2 = 0; r2 < 4; ++r2) {
                        float e = __expf((sc[m0][n0][r2] - m) * scale);
                        sc[m0][n0][r2] = e; sum += e;
                    }
                sum += __shfl_xor(sum, 16);
                sum += __shfl_xor(sum, 32);
                float inv = 1.0f / sum;
                #pragma unroll
                for (int m0 = 0; m0 < 2; ++m0)
                    #pragma unroll
                    for (int r2 = 0; r2 < 4; ++r2) sc[m0][n0][r2] *= inv;
            }
            // Abar[i] = (1/32) * sum_j a[i,j]
            #pragma unroll
            for (int m0 = 0; m0 < 2; ++m0)
                #pragma unroll
                for (int r2 = 0; r2 < 4; ++r2) {
                    float v2 = sc[m0][0][r2] + sc[m0][1][r2];
                    v2 += __shfl_xor(v2, 1);
                    v2 += __shfl_xor(v2, 2);
                    v2 += __shfl_xor(v2, 4);
                    v2 += __shfl_xor(v2, 8);
                    if (l15 == 0)
                        AbarS[wp * 33 + m0 * 16 + quad * 4 + r2] = v2 * (1.0f / kD);
                }
        }
    }
    __syncthreads();

    // ---- Obar[s][w'] = sum_d V[s,d] * Abar[d] ----
    {
        int s = t & 31, wp = (t >> 5) & 7;
        const u16t* vcol = &VT[(wp * kD) * VR + s];
        const float* ab = &AbarS[wp * 33];
        float acc = 0.f;
        #pragma unroll
        for (int d = 0; d < kD; ++d) acc += b2f(vcol[d * VR]) * ab[d];
        ObarS[wp * 33 + s] = acc;
    }
    __syncthreads();

    // ---- final: out[c] = Xbar + f*(bo + Wo*Obar), coalesced over w ----
    {
        const float fac = factor[0];
        int wp = t & 7, cl = t >> 3;
        #pragma unroll
        for (int half = 0; half < 2; ++half) {
            int c = cl + half * 32;
            const float* wrow = Wo + c * kS;       // f32 from global (L1-resident)
            const float* ob = &ObarS[wp * 33];
            float acc = 0.f;
            #pragma unroll
            for (int s2 = 0; s2 < kS; ++s2) acc += wrow[s2] * ob[s2];
            out[((b * kC + c) * kH + h) * kW + w0 + wp] =
                XbarS[c * TW + wp] + fac * (biasS[96 + c] + acc);
        }
    }
}

extern "C" void kernel_launch(void* const* d_in, const int* in_sizes, int n_in,
                              void* d_out, int out_size, void* d_ws, size_t ws_size,
                              hipStream_t stream) {
    const float* x      = (const float*)d_in[0];
    const float* Wk     = (const float*)d_in[1];
    const float* bk     = (const float*)d_in[2];
    const float* Wq     = (const float*)d_in[3];
    const float* bq     = (const float*)d_in[4];
    const float* Wv     = (const float*)d_in[5];
    const float* bv     = (const float*)d_in[6];
    const float* Wo     = (const float*)d_in[7];
    const float* bo     = (const float*)d_in[8];
    const float* factor = (const float*)d_in[9];
    float* out = (float*)d_out;

    dim3 grid(kB * kH * (kW / TW));  // 4096 blocks
    attn_fused<<<grid, NT, 0, stream>>>(x, Wk, bk, Wq, bq, Wv, bv, Wo, bo, factor, out);
}

// Round 4
// 431.472 us; speedup vs baseline: 1.3597x; 1.0422x over previous
//
#include <hip/hip_runtime.h>

// R4: occupancy + bank-conflict round.
//  - LDS cut to exactly 40 KiB -> 4 blocks/CU (16 waves/CU, was 2 blocks).
//    V no longer staged in LDS (kept as packed bf16 C-frags in registers);
//    Obar = V*Abar via in-register FMA + l15 butterfly.
//  - Xbar computed from the B-frags already in registers (kills the 8-way
//    conflicted LDS column-read phase).
//  - Staging lane remap: c-pair on fast lane bits -> conflict-free LDS writes,
//    32-B coalesced pairs preserved on global loads.
//  - 2 barriers total (after staging, before epilogue); proj->scores is
//    same-wave through LDS (in-order DS pipe).
// Math unchanged: out = Xbar + f*(bo + Wo*(V*Abar)), Abar = mean_j softmax_i(K^T Q).

namespace {
constexpr int kB = 8, kC = 64, kD = 32, kH = 64, kW = 64, kS = 32;
constexpr int TW = 8, NT = 256;
constexpr int XR = 72;    // KQX row length in ushorts (144 B = 36 dw)
constexpr int QOFF = 40;  // Q offset (ushorts) within a KQX row (byte 80)

typedef unsigned short u16t;
typedef unsigned int u32t;
typedef __attribute__((ext_vector_type(8))) short bf16x8;
typedef __attribute__((ext_vector_type(4))) float f32x4;
typedef __attribute__((ext_vector_type(4))) short short4v;

__device__ __forceinline__ float b2f(u16t u) {
    union { u32t i; float f; } v; v.i = ((u32t)u) << 16; return v.f;
}
__device__ __forceinline__ u16t f2b(float f) {
    union { u32t i; float f; } v; v.f = f;
    u32t r = v.i + 0x7FFFu + ((v.i >> 16) & 1u);  // RNE
    return (u16t)(r >> 16);
}
__device__ __forceinline__ u32t pack2(float lo, float hi) {
    return (u32t)f2b(lo) | ((u32t)f2b(hi) << 16);
}
__device__ __forceinline__ bf16x8 pack8(const float4 f0, const float4 f1) {
    bf16x8 a;
    a[0] = (short)f2b(f0.x); a[1] = (short)f2b(f0.y);
    a[2] = (short)f2b(f0.z); a[3] = (short)f2b(f0.w);
    a[4] = (short)f2b(f1.x); a[5] = (short)f2b(f1.y);
    a[6] = (short)f2b(f1.z); a[7] = (short)f2b(f1.w);
    return a;
}
} // namespace

__global__ __launch_bounds__(NT, 4) void attn_fused(
    const float* __restrict__ x,
    const float* __restrict__ Wk, const float* __restrict__ bk,
    const float* __restrict__ Wq, const float* __restrict__ bq,
    const float* __restrict__ Wv, const float* __restrict__ bv,
    const float* __restrict__ Wo, const float* __restrict__ bo,
    const float* __restrict__ factor,
    float* __restrict__ out)
{
    __shared__ __align__(16) u16t KQX[256 * XR];  // 36,864 B : X, then K|Q
    __shared__ float XbarS[kC * TW];              //  2,048 B : [c*8+wp]
    __shared__ float AbarS[TW * kD];              //  1,024 B : [wp*32+d]
    __shared__ float ObarS[kS * TW];              //  1,024 B : [s*8+wp]
                                                  //  total 40,960 B -> 4 blk/CU
    const int t = threadIdx.x;
    const int lane = t & 63;
    const int wv = t >> 6;
    const int l15 = lane & 15;
    const int quad = lane >> 4;

    // block swizzle: 8 w-tile siblings of one (b,h) row -> same XCD.
    const int blk = blockIdx.x;
    const int bh = (blk & 7) | ((blk >> 6) << 3);   // 0..511
    const int wt = (blk >> 3) & 7;
    const int b = bh >> 6, h = bh & 63, w0 = wt * TW;

    // ---- stage X -> KQX[n][c] bf16, n = w'*32 + d ----
    // lane map: w4 = bit0, cp = bits1..5, d = it*4 + wave  -> LDS writes are
    // 2-way (free); lane pairs (w4 0/1) give 32-B coalesced global segments.
    {
        const float* xb = x + (size_t)(b * kC * kD) * (kH * kW) + h * kW + w0;
        u32t* dst = (u32t*)KQX;
        #pragma unroll
        for (int it = 0; it < 8; ++it) {
            int unit = it * NT + t;              // 0..2047
            int w4 = unit & 1;
            int cp = (unit >> 1) & 31;
            int d  = unit >> 6;                  // = it*4 + wv
            int c  = cp * 2;
            const float4 fa = *(const float4*)(xb + (size_t)(c * kD + d) * (kH * kW) + w4 * 4);
            const float4 fb = *(const float4*)(xb + (size_t)((c + 1) * kD + d) * (kH * kW) + w4 * 4);
            int r0 = (w4 * 4) * kD + d;
            dst[(r0 + 0 * kD) * 36 + cp] = pack2(fa.x, fb.x);
            dst[(r0 + 1 * kD) * 36 + cp] = pack2(fa.y, fb.y);
            dst[(r0 + 2 * kD) * 36 + cp] = pack2(fa.z, fb.z);
            dst[(r0 + 3 * kD) * 36 + cp] = pack2(fa.w, fb.w);
        }
    }
    __syncthreads();

    // ---- load B-frags for this wave's 64 n-rows ----
    bf16x8 Bf[4][2];
    #pragma unroll
    for (int nt = 0; nt < 4; ++nt) {
        int row = wv * 64 + nt * 16 + l15;
        #pragma unroll
        for (int ks = 0; ks < 2; ++ks)
            Bf[nt][ks] = *(const bf16x8*)&KQX[row * XR + ks * 32 + quad * 8];
    }

    // ---- Xbar from frags: sum over d = (nt&1)*16 + l15 ----
    #pragma unroll
    for (int hh = 0; hh < 2; ++hh) {             // w' = 2*wv + hh
        float xb16[16];
        #pragma unroll
        for (int ks = 0; ks < 2; ++ks)
            #pragma unroll
            for (int e = 0; e < 8; ++e)
                xb16[ks * 8 + e] = b2f((u16t)Bf[hh * 2 + 0][ks][e])
                                 + b2f((u16t)Bf[hh * 2 + 1][ks][e]);
        #pragma unroll
        for (int i = 0; i < 16; ++i) {
            float v = xb16[i];
            v += __shfl_xor(v, 1);
            v += __shfl_xor(v, 2);
            v += __shfl_xor(v, 4);
            v += __shfl_xor(v, 8);
            xb16[i] = v;
        }
        if (l15 == 0) {
            #pragma unroll
            for (int ks = 0; ks < 2; ++ks)
                #pragma unroll
                for (int e = 0; e < 8; ++e) {
                    int c = ks * 32 + quad * 8 + e;
                    XbarS[c * TW + 2 * wv + hh] = xb16[ks * 8 + e] * (1.0f / kD);
                }
        }
    }

    // ---- projections via MFMA; K,Q -> LDS rows (own slice); V -> registers ----
    short4v Vp[2][4];
    #pragma unroll
    for (int p = 0; p < 3; ++p) {
        const float* Wp = (p == 0) ? Wk : (p == 1) ? Wq : Wv;
        const float* bp = (p == 0) ? bk : (p == 1) ? bq : bv;
        bf16x8 Af[2][2];
        float4 bias4[2];
        #pragma unroll
        for (int m0 = 0; m0 < 2; ++m0) {
            #pragma unroll
            for (int ks = 0; ks < 2; ++ks) {
                const float* src = Wp + (m0 * 16 + l15) * kC + ks * 32 + quad * 8;
                Af[m0][ks] = pack8(*(const float4*)src, *(const float4*)(src + 4));
            }
            bias4[m0] = *(const float4*)(bp + m0 * 16 + quad * 4);
        }
        #pragma unroll
        for (int m0 = 0; m0 < 2; ++m0) {
            #pragma unroll
            for (int nt = 0; nt < 4; ++nt) {
                f32x4 acc = {0.f, 0.f, 0.f, 0.f};
                acc = __builtin_amdgcn_mfma_f32_16x16x32_bf16(Af[m0][0], Bf[nt][0], acc, 0, 0, 0);
                acc = __builtin_amdgcn_mfma_f32_16x16x32_bf16(Af[m0][1], Bf[nt][1], acc, 0, 0, 0);
                short4v pk;
                pk.x = (short)f2b(acc[0] + bias4[m0].x);
                pk.y = (short)f2b(acc[1] + bias4[m0].y);
                pk.z = (short)f2b(acc[2] + bias4[m0].z);
                pk.w = (short)f2b(acc[3] + bias4[m0].w);
                if (p < 2) {
                    int row = wv * 64 + nt * 16 + l15;
                    *(short4v*)&KQX[row * XR + (p == 0 ? 0 : QOFF) + m0 * 16 + quad * 4] = pk;
                } else {
                    Vp[m0][nt] = pk;
                }
            }
        }
    }
    // no barrier: scores read only this wave's rows; DS pipe is in-order per wave.

    // ---- scores + softmax + Abar + Obar, 2 sites per wave ----
    {
        const float scale = 0.17677669529663687f;  // 1/sqrt(32)
        #pragma unroll
        for (int si = 0; si < 2; ++si) {
            int wp = wv * 2 + si;                  // site (w') 0..7
            bf16x8 Ka[2], Qb[2];
            #pragma unroll
            for (int m0 = 0; m0 < 2; ++m0)
                Ka[m0] = *(const bf16x8*)&KQX[(wp * kD + m0 * 16 + l15) * XR + quad * 8];
            #pragma unroll
            for (int n0 = 0; n0 < 2; ++n0)
                Qb[n0] = *(const bf16x8*)&KQX[(wp * kD + n0 * 16 + l15) * XR + QOFF + quad * 8];
            f32x4 sc[2][2];
            #pragma unroll
            for (int m0 = 0; m0 < 2; ++m0)
                #pragma unroll
                for (int n0 = 0; n0 < 2; ++n0) {
                    f32x4 z = {0.f, 0.f, 0.f, 0.f};
                    sc[m0][n0] = __builtin_amdgcn_mfma_f32_16x16x32_bf16(Ka[m0], Qb[n0], z, 0, 0, 0);
                }
            // softmax over i (rows) per column j = n0*16 + l15
            #pragma unroll
            for (int n0 = 0; n0 < 2; ++n0) {
                float m = sc[0][n0][0];
                #pragma unroll
                for (int m0 = 0; m0 < 2; ++m0)
                    #pragma unroll
                    for (int r2 = 0; r2 < 4; ++r2) m = fmaxf(m, sc[m0][n0][r2]);
                m = fmaxf(m, __shfl_xor(m, 16));
                m = fmaxf(m, __shfl_xor(m, 32));
                float sum = 0.f;
                #pragma unroll
                for (int m0 = 0; m0 < 2; ++m0)
                    #pragma unroll
                    for (int r2 = 0; r2 < 4; ++r2) {
                        float e = __expf((sc[m0][n0][r2] - m) * scale);
                        sc[m0][n0][r2] = e; sum += e;
                    }
                sum += __shfl_xor(sum, 16);
                sum += __shfl_xor(sum, 32);
                float inv = 1.0f / sum;
                #pragma unroll
                for (int m0 = 0; m0 < 2; ++m0)
                    #pragma unroll
                    for (int r2 = 0; r2 < 4; ++r2) sc[m0][n0][r2] *= inv;
            }
            // Abar[i] = (1/32) * sum_j a[i,j]  -> AbarS[wp*32 + i]
            #pragma unroll
            for (int m0 = 0; m0 < 2; ++m0)
                #pragma unroll
                for (int r2 = 0; r2 < 4; ++r2) {
                    float v2 = sc[m0][0][r2] + sc[m0][1][r2];
                    v2 += __shfl_xor(v2, 1);
                    v2 += __shfl_xor(v2, 2);
                    v2 += __shfl_xor(v2, 4);
                    v2 += __shfl_xor(v2, 8);
                    if (l15 == 0)
                        AbarS[wp * kD + m0 * 16 + quad * 4 + r2] = v2 * (1.0f / kD);
                }
            // Obar[s] = sum_d V[s,d]*Abar[d]; d = g*16 + l15, V from C-frags
            {
                float ab0 = AbarS[wp * kD + l15];
                float ab1 = AbarS[wp * kD + 16 + l15];
                #pragma unroll
                for (int m0 = 0; m0 < 2; ++m0)
                    #pragma unroll
                    for (int r2 = 0; r2 < 4; ++r2) {
                        float v = b2f((u16t)Vp[m0][2 * si + 0][r2]) * ab0
                                + b2f((u16t)Vp[m0][2 * si + 1][r2]) * ab1;
                        v += __shfl_xor(v, 1);
                        v += __shfl_xor(v, 2);
                        v += __shfl_xor(v, 4);
                        v += __shfl_xor(v, 8);
                        if (l15 == 0)
                            ObarS[(m0 * 16 + quad * 4 + r2) * TW + wp] = v;
                    }
            }
        }
    }
    __syncthreads();

    // ---- final: out[c] = Xbar + f*(bo + Wo*Obar), coalesced over w ----
    {
        const float fac = factor[0];
        int wp = t & 7, cl = t >> 3;
        #pragma unroll
        for (int half = 0; half < 2; ++half) {
            int c = cl + half * 32;
            const float4* wrow = (const float4*)(Wo + c * kS);
            float acc = 0.f;
            #pragma unroll
            for (int s4 = 0; s4 < 8; ++s4) {
                float4 w4 = wrow[s4];
                acc += w4.x * ObarS[(s4 * 4 + 0) * TW + wp];
                acc += w4.y * ObarS[(s4 * 4 + 1) * TW + wp];
                acc += w4.z * ObarS[(s4 * 4 + 2) * TW + wp];
                acc += w4.w * ObarS[(s4 * 4 + 3) * TW + wp];
            }
            out[((b * kC + c) * kH + h) * kW + w0 + wp] =
                XbarS[c * TW + wp] + fac * (bo[c] + acc);
        }
    }
}

extern "C" void kernel_launch(void* const* d_in, const int* in_sizes, int n_in,
                              void* d_out, int out_size, void* d_ws, size_t ws_size,
                              hipStream_t stream) {
    const float* x      = (const float*)d_in[0];
    const float* Wk     = (const float*)d_in[1];
    const float* bk     = (const float*)d_in[2];
    const float* Wq     = (const float*)d_in[3];
    const float* bq     = (const float*)d_in[4];
    const float* Wv     = (const float*)d_in[5];
    const float* bv     = (const float*)d_in[6];
    const float* Wo     = (const float*)d_in[7];
    const float* bo     = (const float*)d_in[8];
    const float* factor = (const float*)d_in[9];
    float* out = (float*)d_out;

    dim3 grid(kB * kH * (kW / TW));  // 4096 blocks
    attn_fused<<<grid, NT, 0, stream>>>(x, Wk, bk, Wq, bq, Wv, bv, Wo, bo, factor, out);
}

// Round 5
// 427.898 us; speedup vs baseline: 1.3711x; 1.0084x over previous
//
#include <hip/hip_runtime.h>

// R5: latency round.
//  - Staging loads hoisted into register arrays (16 float4 in flight; R4's
//    VGPR=64 showed the compiler serialized 8 waitcnt-load pairs).
//  - XOR-swizzled KQX rows (64 ushorts/row, 16B granule g ^= row&7):
//    32 KiB, conflict-free for staging writes, b128 frag reads, K/Q frag
//    writes, and score frag reads.  K cols [0,32), Q cols [32,64).
//  - Softmax max-subtraction dropped (scores bounded ~|10|; exp2 arg < 3),
//    rcp for 1/sum -> removes the serial max-reduce cross-row shuffles.
//  - Obar stored [wp][s] -> epilogue reads ds_read_b128.
// Math: out = Xbar + f*(bo + Wo*(V*Abar)), Abar = mean_j softmax_i(K^T Q).
// LDS = 32768 + 2048 + 1024 + 1024 = 36,864 B -> 4 blocks/CU.

namespace {
constexpr int kB = 8, kC = 64, kD = 32, kH = 64, kW = 64, kS = 32;
constexpr int kHW = kH * kW;
constexpr int TW = 8, NT = 256;

typedef unsigned short u16t;
typedef unsigned int u32t;
typedef __attribute__((ext_vector_type(8))) short bf16x8;
typedef __attribute__((ext_vector_type(4))) float f32x4;
typedef __attribute__((ext_vector_type(4))) short short4v;

__device__ __forceinline__ float b2f(u16t u) {
    union { u32t i; float f; } v; v.i = ((u32t)u) << 16; return v.f;
}
__device__ __forceinline__ u16t f2b(float f) {
    union { u32t i; float f; } v; v.f = f;
    u32t r = v.i + 0x7FFFu + ((v.i >> 16) & 1u);  // RNE
    return (u16t)(r >> 16);
}
__device__ __forceinline__ u32t pack2(float lo, float hi) {
    return (u32t)f2b(lo) | ((u32t)f2b(hi) << 16);
}
__device__ __forceinline__ bf16x8 pack8(const float4 f0, const float4 f1) {
    bf16x8 a;
    a[0] = (short)f2b(f0.x); a[1] = (short)f2b(f0.y);
    a[2] = (short)f2b(f0.z); a[3] = (short)f2b(f0.w);
    a[4] = (short)f2b(f1.x); a[5] = (short)f2b(f1.y);
    a[6] = (short)f2b(f1.z); a[7] = (short)f2b(f1.w);
    return a;
}
} // namespace

__global__ __launch_bounds__(NT, 4) void attn_fused(
    const float* __restrict__ x,
    const float* __restrict__ Wk, const float* __restrict__ bk,
    const float* __restrict__ Wq, const float* __restrict__ bq,
    const float* __restrict__ Wv, const float* __restrict__ bv,
    const float* __restrict__ Wo, const float* __restrict__ bo,
    const float* __restrict__ factor,
    float* __restrict__ out)
{
    // KQX row n (0..255): 64 ushorts = 8 granules of 16B; physical granule =
    // (logical granule) ^ (n & 7).  X cols = c 0..63; later K cols s -> [0,32),
    // Q cols 32+s -> [32,64).
    __shared__ __align__(16) u16t KQX[256 * 64];   // 32,768 B
    __shared__ float XbarS[TW * kC];               //  2,048 B : [wp][c]
    __shared__ float AbarS[TW * kD];               //  1,024 B : [wp][i]
    __shared__ __align__(16) float ObarS[TW * kS]; //  1,024 B : [wp][s]

    const int t = threadIdx.x;
    const int lane = t & 63;
    const int wv = t >> 6;
    const int l15 = lane & 15;
    const int quad = lane >> 4;

    // block swizzle: 8 w-tile siblings of one (b,h) row -> same XCD.
    const int blk = blockIdx.x;
    const int bh = (blk & 7) | ((blk >> 6) << 3);   // 0..511
    const int wt = (blk >> 3) & 7;
    const int b = bh >> 6, h = bh & 63, w0 = wt * TW;

    // ---- stage X: all 16 loads issued before any consumption ----
    // thread map: w4 = t&1, cp = (t>>1)&31 (c-pair), d = wv + it*4.
    {
        const float* xb = x + (size_t)(b * kC * kD) * kHW + h * kW + w0;
        const int w4 = t & 1, cp = (t >> 1) & 31;
        const float* p0 = xb + (size_t)((cp * 2) * kD + wv) * kHW + w4 * 4;
        const float* p1 = p0 + (size_t)kD * kHW;
        float4 fa[8], fb[8];
        #pragma unroll
        for (int it = 0; it < 8; ++it) {
            fa[it] = *(const float4*)(p0 + (size_t)(it * 4) * kHW);
            fb[it] = *(const float4*)(p1 + (size_t)(it * 4) * kHW);
        }
        u32t* dst = (u32t*)KQX;
        const int gsw = cp >> 2;                 // logical granule of this dword
        const int gin = cp & 3;                  // dword within granule
        #pragma unroll
        for (int it = 0; it < 8; ++it) {
            int d = wv + it * 4;
            int sw = d & 7;                      // row&7 (uniform across wave)
            int pg = (gsw ^ sw) * 4 + gin;       // physical dword within row
            int r0 = w4 * 128 + d;               // n = (w4*4+e)*32 + d
            dst[(r0 + 0 * 32) * 32 + pg] = pack2(fa[it].x, fb[it].x);
            dst[(r0 + 1 * 32) * 32 + pg] = pack2(fa[it].y, fb[it].y);
            dst[(r0 + 2 * 32) * 32 + pg] = pack2(fa[it].z, fb[it].z);
            dst[(r0 + 3 * 32) * 32 + pg] = pack2(fa[it].w, fb[it].w);
        }
    }
    __syncthreads();

    // ---- load B-frags for this wave's 64 n-rows (swizzled granules) ----
    bf16x8 Bf[4][2];
    #pragma unroll
    for (int nt = 0; nt < 4; ++nt) {
        int row = wv * 64 + nt * 16 + l15;
        int sw = l15 & 7;
        #pragma unroll
        for (int ks = 0; ks < 2; ++ks)
            Bf[nt][ks] = *(const bf16x8*)&KQX[row * 64 + ((ks * 4 + quad) ^ sw) * 8];
    }

    // ---- Xbar from frags: sum over d = (nt&1)*16 + l15 (dpp butterflies) ----
    #pragma unroll
    for (int hh = 0; hh < 2; ++hh) {             // w' = 2*wv + hh
        float xb16[16];
        #pragma unroll
        for (int ks = 0; ks < 2; ++ks)
            #pragma unroll
            for (int e = 0; e < 8; ++e)
                xb16[ks * 8 + e] = b2f((u16t)Bf[hh * 2 + 0][ks][e])
                                 + b2f((u16t)Bf[hh * 2 + 1][ks][e]);
        #pragma unroll
        for (int i = 0; i < 16; ++i) {
            float v = xb16[i];
            v += __shfl_xor(v, 1);
            v += __shfl_xor(v, 2);
            v += __shfl_xor(v, 4);
            v += __shfl_xor(v, 8);
            xb16[i] = v;
        }
        if (l15 == 0) {
            int wp = 2 * wv + hh;
            #pragma unroll
            for (int ks = 0; ks < 2; ++ks)
                #pragma unroll
                for (int e = 0; e < 8; ++e)
                    XbarS[wp * kC + ks * 32 + quad * 8 + e] = xb16[ks * 8 + e] * (1.0f / kD);
        }
    }

    // ---- projections via MFMA; K,Q -> own LDS rows; V -> registers ----
    short4v Vp[2][4];
    #pragma unroll
    for (int p = 0; p < 3; ++p) {
        const float* Wp = (p == 0) ? Wk : (p == 1) ? Wq : Wv;
        const float* bp = (p == 0) ? bk : (p == 1) ? bq : bv;
        bf16x8 Af[2][2];
        float4 bias4[2];
        #pragma unroll
        for (int m0 = 0; m0 < 2; ++m0) {
            #pragma unroll
            for (int ks = 0; ks < 2; ++ks) {
                const float* src = Wp + (m0 * 16 + l15) * kC + ks * 32 + quad * 8;
                Af[m0][ks] = pack8(*(const float4*)src, *(const float4*)(src + 4));
            }
            bias4[m0] = *(const float4*)(bp + m0 * 16 + quad * 4);
        }
        #pragma unroll
        for (int m0 = 0; m0 < 2; ++m0) {
            #pragma unroll
            for (int nt = 0; nt < 4; ++nt) {
                f32x4 acc = {0.f, 0.f, 0.f, 0.f};
                acc = __builtin_amdgcn_mfma_f32_16x16x32_bf16(Af[m0][0], Bf[nt][0], acc, 0, 0, 0);
                acc = __builtin_amdgcn_mfma_f32_16x16x32_bf16(Af[m0][1], Bf[nt][1], acc, 0, 0, 0);
                short4v pk;
                pk.x = (short)f2b(acc[0] + bias4[m0].x);
                pk.y = (short)f2b(acc[1] + bias4[m0].y);
                pk.z = (short)f2b(acc[2] + bias4[m0].z);
                pk.w = (short)f2b(acc[3] + bias4[m0].w);
                if (p < 2) {
                    int row = wv * 64 + nt * 16 + l15;
                    int g = (p == 0 ? 0 : 4) + m0 * 2 + (quad >> 1);
                    *(short4v*)&KQX[row * 64 + ((g ^ (l15 & 7)) * 8) + (quad & 1) * 4] = pk;
                } else {
                    Vp[m0][nt] = pk;
                }
            }
        }
    }
    // no barrier: scores read only this wave's own rows (in-order DS pipe).

    // ---- scores + softmax (no max-sub) + Abar + Obar, 2 sites/wave ----
    {
        const float kScaleLog2e = 0.25501700249569946f;  // (1/sqrt(32))*log2(e)
        #pragma unroll
        for (int si = 0; si < 2; ++si) {
            int wp = wv * 2 + si;                  // site (w') 0..7
            bf16x8 Ka[2], Qb[2];
            #pragma unroll
            for (int m0 = 0; m0 < 2; ++m0) {
                int rr = wp * 32 + m0 * 16 + l15;
                Ka[m0] = *(const bf16x8*)&KQX[rr * 64 + ((quad ^ (l15 & 7)) * 8)];
            }
            #pragma unroll
            for (int n0 = 0; n0 < 2; ++n0) {
                int rr = wp * 32 + n0 * 16 + l15;
                Qb[n0] = *(const bf16x8*)&KQX[rr * 64 + (((4 + quad) ^ (l15 & 7)) * 8)];
            }
            f32x4 sc[2][2];
            #pragma unroll
            for (int m0 = 0; m0 < 2; ++m0)
                #pragma unroll
                for (int n0 = 0; n0 < 2; ++n0) {
                    f32x4 z = {0.f, 0.f, 0.f, 0.f};
                    sc[m0][n0] = __builtin_amdgcn_mfma_f32_16x16x32_bf16(Ka[m0], Qb[n0], z, 0, 0, 0);
                }
            // softmax over i per column j = n0*16 + l15 (no max subtraction;
            // |scores/sqrt(s)| < ~3 -> exp2 safe)
            #pragma unroll
            for (int n0 = 0; n0 < 2; ++n0) {
                float sum = 0.f;
                #pragma unroll
                for (int m0 = 0; m0 < 2; ++m0)
                    #pragma unroll
                    for (int r2 = 0; r2 < 4; ++r2) {
                        float e = exp2f(sc[m0][n0][r2] * kScaleLog2e);
                        sc[m0][n0][r2] = e; sum += e;
                    }
                sum += __shfl_xor(sum, 16);
                sum += __shfl_xor(sum, 32);
                float inv = __builtin_amdgcn_rcpf(sum);
                #pragma unroll
                for (int m0 = 0; m0 < 2; ++m0)
                    #pragma unroll
                    for (int r2 = 0; r2 < 4; ++r2) sc[m0][n0][r2] *= inv;
            }
            // Abar[i] = (1/32) * sum_j a[i,j]  -> AbarS[wp][i]
            #pragma unroll
            for (int m0 = 0; m0 < 2; ++m0)
                #pragma unroll
                for (int r2 = 0; r2 < 4; ++r2) {
                    float v2 = sc[m0][0][r2] + sc[m0][1][r2];
                    v2 += __shfl_xor(v2, 1);
                    v2 += __shfl_xor(v2, 2);
                    v2 += __shfl_xor(v2, 4);
                    v2 += __shfl_xor(v2, 8);
                    if (l15 == 0)
                        AbarS[wp * kD + m0 * 16 + quad * 4 + r2] = v2 * (1.0f / kD);
                }
            // Obar[s] = sum_d V[s,d]*Abar[d] (V C-frags; d = g*16+l15)
            {
                float ab0 = AbarS[wp * kD + l15];
                float ab1 = AbarS[wp * kD + 16 + l15];
                #pragma unroll
                for (int m0 = 0; m0 < 2; ++m0)
                    #pragma unroll
                    for (int r2 = 0; r2 < 4; ++r2) {
                        float v = b2f((u16t)Vp[m0][2 * si + 0][r2]) * ab0
                                + b2f((u16t)Vp[m0][2 * si + 1][r2]) * ab1;
                        v += __shfl_xor(v, 1);
                        v += __shfl_xor(v, 2);
                        v += __shfl_xor(v, 4);
                        v += __shfl_xor(v, 8);
                        if (l15 == 0)
                            ObarS[wp * kS + m0 * 16 + quad * 4 + r2] = v;
                    }
            }
        }
    }
    __syncthreads();

    // ---- final: out[c] = Xbar + f*(bo + Wo*Obar), coalesced over w ----
    {
        const float fac = factor[0];
        int wp = t & 7, cl = t >> 3;
        const float4* obp = (const float4*)&ObarS[wp * kS];
        float4 ob4[8];
        #pragma unroll
        for (int s4 = 0; s4 < 8; ++s4) ob4[s4] = obp[s4];
        #pragma unroll
        for (int half = 0; half < 2; ++half) {
            int c = cl + half * 32;
            const float4* wrow = (const float4*)(Wo + c * kS);
            float acc = 0.f;
            #pragma unroll
            for (int s4 = 0; s4 < 8; ++s4) {
                float4 w4 = wrow[s4];
                acc += w4.x * ob4[s4].x;
                acc += w4.y * ob4[s4].y;
                acc += w4.z * ob4[s4].z;
                acc += w4.w * ob4[s4].w;
            }
            out[((b * kC + c) * kH + h) * kW + w0 + wp] =
                XbarS[wp * kC + c] + fac * (bo[c] + acc);
        }
    }
}

extern "C" void kernel_launch(void* const* d_in, const int* in_sizes, int n_in,
                              void* d_out, int out_size, void* d_ws, size_t ws_size,
                              hipStream_t stream) {
    const float* x      = (const float*)d_in[0];
    const float* Wk     = (const float*)d_in[1];
    const float* bk     = (const float*)d_in[2];
    const float* Wq     = (const float*)d_in[3];
    const float* bq     = (const float*)d_in[4];
    const float* Wv     = (const float*)d_in[5];
    const float* bv     = (const float*)d_in[6];
    const float* Wo     = (const float*)d_in[7];
    const float* bo     = (const float*)d_in[8];
    const float* factor = (const float*)d_in[9];
    float* out = (float*)d_out;

    dim3 grid(kB * kH * (kW / TW));  // 4096 blocks
    attn_fused<<<grid, NT, 0, stream>>>(x, Wk, bk, Wq, bq, Wv, bv, Wo, bo, factor, out);
}

// Round 6
// 421.092 us; speedup vs baseline: 1.3933x; 1.0162x over previous
//
#include <hip/hip_runtime.h>

// R6: instruction-count round.
//  - bf16 conversion via v_cvt_pk_bf16_f32 (gfx950 HW op; guarded builtin)
//    replacing ~5-op manual RNE sequences (~1.2k VALU/wave removed).
//  - Xbar via staging-thread partial sums (f32 in-register over the 8 d's a
//    thread already holds) + 4KB LDS partials; kills 128 ds_bpermute/wave.
//  - V stays f32 in C-frag registers (no bf16 round-trip; VALU-only consumer).
//  - sched_barrier(0) after the 16 staging loads forces all loads in flight
//    (R4/R5: compiler re-serialized them, VGPR stayed 64).
//  - Weight A-frags prefetched+packed before the barrier; ObarS rows padded
//    to 36 floats (epilogue b128 reads conflict-free).
// Math: out = Xbar + f*(bo + Wo*(V*Abar)), Abar = mean_j softmax_i(K^T Q).
// LDS = 32768 + 4096 + 1024 + 1152 = 39,040 B -> 4 blocks/CU.

namespace {
constexpr int kB = 8, kC = 64, kD = 32, kH = 64, kW = 64, kS = 32;
constexpr int kHW = kH * kW;
constexpr int TW = 8, NT = 256;

typedef unsigned short u16t;
typedef unsigned int u32t;
typedef __attribute__((ext_vector_type(8))) short bf16x8;
typedef __attribute__((ext_vector_type(4))) float f32x4;

#if defined(__has_builtin)
#if __has_builtin(__builtin_amdgcn_cvt_pk_bf16_f32)
#define HAS_CVT_PK_BF16 1
#endif
#endif

__device__ __forceinline__ u32t pack2(float lo, float hi) {
#ifdef HAS_CVT_PK_BF16
    typedef __attribute__((ext_vector_type(2))) __bf16 v2bf;
    union { v2bf v; u32t u; } cv;
    cv.v = __builtin_amdgcn_cvt_pk_bf16_f32(lo, hi);
    return cv.u;
#else
    union { u32t i; float f; } a, b;
    a.f = lo; b.f = hi;
    u32t ra = a.i + 0x7FFFu + ((a.i >> 16) & 1u);
    u32t rb = b.i + 0x7FFFu + ((b.i >> 16) & 1u);
    return (ra >> 16) | (rb & 0xFFFF0000u);
#endif
}
__device__ __forceinline__ bf16x8 pack8(const float4 f0, const float4 f1) {
    union { bf16x8 v; u32t u[4]; } r;
    r.u[0] = pack2(f0.x, f0.y); r.u[1] = pack2(f0.z, f0.w);
    r.u[2] = pack2(f1.x, f1.y); r.u[3] = pack2(f1.z, f1.w);
    return r.v;
}
// select bf16 half of a packed pair as f32
__device__ __forceinline__ float bsel(u32t q, int odd) {
    union { u32t i; float f; } v;
    v.i = odd ? (q & 0xFFFF0000u) : (q << 16);
    return v.f;
}
} // namespace

__global__ __launch_bounds__(NT, 4) void attn_fused(
    const float* __restrict__ x,
    const float* __restrict__ Wk, const float* __restrict__ bk,
    const float* __restrict__ Wq, const float* __restrict__ bq,
    const float* __restrict__ Wv, const float* __restrict__ bv,
    const float* __restrict__ Wo, const float* __restrict__ bo,
    const float* __restrict__ factor,
    float* __restrict__ out)
{
    // KQX row n (0..255): 64 ushorts; 16B granule XOR-swizzled by (n&7).
    __shared__ __align__(16) u16t KQX[256 * 64];   // 32,768 B
    __shared__ u32t XbP[4 * 256];                  //  4,096 B : [wv][w4][e][cp], bf16 pair (c even|odd)
    __shared__ float AbarS[TW * kD];               //  1,024 B : [wp][i]
    __shared__ __align__(16) float ObarS[TW * 36]; //  1,152 B : [wp][s] pad 36

    const int t = threadIdx.x;
    const int lane = t & 63;
    const int wv = t >> 6;
    const int l15 = lane & 15;
    const int quad = lane >> 4;

    // block swizzle: 8 w-tile siblings of one (b,h) row -> same XCD.
    const int blk = blockIdx.x;
    const int bh = (blk & 7) | ((blk >> 6) << 3);   // 0..511
    const int wt = (blk >> 3) & 7;
    const int b = bh >> 6, h = bh & 63, w0 = wt * TW;

    // ---- stage X: 16 loads forced in flight, then consume ----
    // thread map: w4 = t&1, cp = (t>>1)&31 (c-pair), d = wv + it*4.
    {
        const float* xb = x + (size_t)(b * kC * kD) * kHW + h * kW + w0;
        const int w4 = t & 1, cp = (t >> 1) & 31;
        const float* p0 = xb + (size_t)((cp * 2) * kD + wv) * kHW + w4 * 4;
        const float* p1 = p0 + (size_t)kD * kHW;
        float4 fa[8], fb[8];
        #pragma unroll
        for (int it = 0; it < 8; ++it) {
            fa[it] = *(const float4*)(p0 + (size_t)(it * 4) * kHW);
            fb[it] = *(const float4*)(p1 + (size_t)(it * 4) * kHW);
        }
        __builtin_amdgcn_sched_barrier(0);   // all 16 loads issued before use

        // Xbar partials over this thread's 8 d's (f32), packed bf16 to LDS
        float4 sA = fa[0], sB = fb[0];
        #pragma unroll
        for (int it = 1; it < 8; ++it) {
            sA.x += fa[it].x; sA.y += fa[it].y; sA.z += fa[it].z; sA.w += fa[it].w;
            sB.x += fb[it].x; sB.y += fb[it].y; sB.z += fb[it].z; sB.w += fb[it].w;
        }
        XbP[wv * 256 + w4 * 128 + 0 * 32 + cp] = pack2(sA.x, sB.x);
        XbP[wv * 256 + w4 * 128 + 1 * 32 + cp] = pack2(sA.y, sB.y);
        XbP[wv * 256 + w4 * 128 + 2 * 32 + cp] = pack2(sA.z, sB.z);
        XbP[wv * 256 + w4 * 128 + 3 * 32 + cp] = pack2(sA.w, sB.w);

        // pack + swizzled staging writes
        u32t* dst = (u32t*)KQX;
        const int gsw = cp >> 2, gin = cp & 3;
        #pragma unroll
        for (int it = 0; it < 8; ++it) {
            int d = wv + it * 4;
            int sw = d & 7;
            int pg = (gsw ^ sw) * 4 + gin;
            int r0 = w4 * 128 + d;
            dst[(r0 + 0 * 32) * 32 + pg] = pack2(fa[it].x, fb[it].x);
            dst[(r0 + 1 * 32) * 32 + pg] = pack2(fa[it].y, fb[it].y);
            dst[(r0 + 2 * 32) * 32 + pg] = pack2(fa[it].z, fb[it].z);
            dst[(r0 + 3 * 32) * 32 + pg] = pack2(fa[it].w, fb[it].w);
        }
    }

    // ---- prefetch + pack weight A-frags and biases (overlaps barrier) ----
    bf16x8 Af[3][2][2];
    float4 bias4[3][2];
    {
        const float* Wp[3] = {Wk, Wq, Wv};
        const float* bp[3] = {bk, bq, bv};
        #pragma unroll
        for (int p = 0; p < 3; ++p) {
            #pragma unroll
            for (int m0 = 0; m0 < 2; ++m0) {
                #pragma unroll
                for (int ks = 0; ks < 2; ++ks) {
                    const float* src = Wp[p] + (m0 * 16 + l15) * kC + ks * 32 + quad * 8;
                    Af[p][m0][ks] = pack8(*(const float4*)src, *(const float4*)(src + 4));
                }
                bias4[p][m0] = *(const float4*)(bp[p] + m0 * 16 + quad * 4);
            }
        }
    }
    __syncthreads();

    // ---- load B-frags for this wave's 64 n-rows (swizzled granules) ----
    bf16x8 Bf[4][2];
    #pragma unroll
    for (int nt = 0; nt < 4; ++nt) {
        int row = wv * 64 + nt * 16 + l15;
        int sw = l15 & 7;
        #pragma unroll
        for (int ks = 0; ks < 2; ++ks)
            Bf[nt][ks] = *(const bf16x8*)&KQX[row * 64 + ((ks * 4 + quad) ^ sw) * 8];
    }

    // ---- projections via MFMA; K,Q -> own LDS rows (bf16); V -> f32 regs ----
    f32x4 Vf[2][4];
    #pragma unroll
    for (int p = 0; p < 3; ++p) {
        #pragma unroll
        for (int m0 = 0; m0 < 2; ++m0) {
            #pragma unroll
            for (int nt = 0; nt < 4; ++nt) {
                f32x4 acc = {0.f, 0.f, 0.f, 0.f};
                acc = __builtin_amdgcn_mfma_f32_16x16x32_bf16(Af[p][m0][0], Bf[nt][0], acc, 0, 0, 0);
                acc = __builtin_amdgcn_mfma_f32_16x16x32_bf16(Af[p][m0][1], Bf[nt][1], acc, 0, 0, 0);
                if (p < 2) {
                    u32t lo = pack2(acc[0] + bias4[p][m0].x, acc[1] + bias4[p][m0].y);
                    u32t hi = pack2(acc[2] + bias4[p][m0].z, acc[3] + bias4[p][m0].w);
                    int row = wv * 64 + nt * 16 + l15;
                    int g = (p == 0 ? 0 : 4) + m0 * 2 + (quad >> 1);
                    uint2 pr; pr.x = lo; pr.y = hi;
                    *(uint2*)&KQX[row * 64 + ((g ^ (l15 & 7)) * 8) + (quad & 1) * 4] = pr;
                } else {
                    Vf[m0][nt][0] = acc[0] + bias4[2][m0].x;
                    Vf[m0][nt][1] = acc[1] + bias4[2][m0].y;
                    Vf[m0][nt][2] = acc[2] + bias4[2][m0].z;
                    Vf[m0][nt][3] = acc[3] + bias4[2][m0].w;
                }
            }
        }
    }
    // no barrier: scores read only this wave's own rows (in-order DS pipe).

    // ---- scores + softmax (no max-sub) + Abar + Obar, 2 sites/wave ----
    {
        const float kScaleLog2e = 0.25501700249569946f;  // (1/sqrt(32))*log2(e)
        #pragma unroll
        for (int si = 0; si < 2; ++si) {
            int wp = wv * 2 + si;                  // site (w') 0..7
            bf16x8 Ka[2], Qb[2];
            #pragma unroll
            for (int m0 = 0; m0 < 2; ++m0) {
                int rr = wp * 32 + m0 * 16 + l15;
                Ka[m0] = *(const bf16x8*)&KQX[rr * 64 + ((quad ^ (l15 & 7)) * 8)];
            }
            #pragma unroll
            for (int n0 = 0; n0 < 2; ++n0) {
                int rr = wp * 32 + n0 * 16 + l15;
                Qb[n0] = *(const bf16x8*)&KQX[rr * 64 + (((4 + quad) ^ (l15 & 7)) * 8)];
            }
            f32x4 sc[2][2];
            #pragma unroll
            for (int m0 = 0; m0 < 2; ++m0)
                #pragma unroll
                for (int n0 = 0; n0 < 2; ++n0) {
                    f32x4 z = {0.f, 0.f, 0.f, 0.f};
                    sc[m0][n0] = __builtin_amdgcn_mfma_f32_16x16x32_bf16(Ka[m0], Qb[n0], z, 0, 0, 0);
                }
            // softmax over i per column j = n0*16 + l15
            #pragma unroll
            for (int n0 = 0; n0 < 2; ++n0) {
                float sum = 0.f;
                #pragma unroll
                for (int m0 = 0; m0 < 2; ++m0)
                    #pragma unroll
                    for (int r2 = 0; r2 < 4; ++r2) {
                        float e = exp2f(sc[m0][n0][r2] * kScaleLog2e);
                        sc[m0][n0][r2] = e; sum += e;
                    }
                sum += __shfl_xor(sum, 16);
                sum += __shfl_xor(sum, 32);
                float inv = __builtin_amdgcn_rcpf(sum);
                #pragma unroll
                for (int m0 = 0; m0 < 2; ++m0)
                    #pragma unroll
                    for (int r2 = 0; r2 < 4; ++r2) sc[m0][n0][r2] *= inv;
            }
            // Abar[i] = (1/32) * sum_j a[i,j]  -> AbarS[wp][i]
            #pragma unroll
            for (int m0 = 0; m0 < 2; ++m0)
                #pragma unroll
                for (int r2 = 0; r2 < 4; ++r2) {
                    float v2 = sc[m0][0][r2] + sc[m0][1][r2];
                    v2 += __shfl_xor(v2, 1);
                    v2 += __shfl_xor(v2, 2);
                    v2 += __shfl_xor(v2, 4);
                    v2 += __shfl_xor(v2, 8);
                    if (l15 == 0)
                        AbarS[wp * kD + m0 * 16 + quad * 4 + r2] = v2 * (1.0f / kD);
                }
            // Obar[s] = sum_d V[s,d]*Abar[d] (V f32 C-frags; d = g*16+l15)
            {
                float ab0 = AbarS[wp * kD + l15];
                float ab1 = AbarS[wp * kD + 16 + l15];
                #pragma unroll
                for (int m0 = 0; m0 < 2; ++m0)
                    #pragma unroll
                    for (int r2 = 0; r2 < 4; ++r2) {
                        float v = Vf[m0][2 * si + 0][r2] * ab0
                                + Vf[m0][2 * si + 1][r2] * ab1;
                        v += __shfl_xor(v, 1);
                        v += __shfl_xor(v, 2);
                        v += __shfl_xor(v, 4);
                        v += __shfl_xor(v, 8);
                        if (l15 == 0)
                            ObarS[wp * 36 + m0 * 16 + quad * 4 + r2] = v;
                    }
            }
        }
    }
    __syncthreads();

    // ---- final: out[c] = Xbar + f*(bo + Wo*Obar), coalesced over w ----
    {
        const float fac = factor[0];
        const int wp = t & 7, cl = t >> 3;
        const float4* obp = (const float4*)&ObarS[wp * 36];
        float4 ob4[8];
        #pragma unroll
        for (int s4 = 0; s4 < 8; ++s4) ob4[s4] = obp[s4];
        const int xidx = (wp >> 2) * 128 + (wp & 3) * 32;
        const int odd = cl & 1;
        #pragma unroll
        for (int half = 0; half < 2; ++half) {
            int c = cl + half * 32;
            int cpi = (cl >> 1) + half * 16;
            float xbar = bsel(XbP[0 * 256 + xidx + cpi], odd)
                       + bsel(XbP[1 * 256 + xidx + cpi], odd)
                       + bsel(XbP[2 * 256 + xidx + cpi], odd)
                       + bsel(XbP[3 * 256 + xidx + cpi], odd);
            xbar *= (1.0f / kD);
            const float4* wrow = (const float4*)(Wo + c * kS);
            float acc = 0.f;
            #pragma unroll
            for (int s4 = 0; s4 < 8; ++s4) {
                float4 w4 = wrow[s4];
                acc += w4.x * ob4[s4].x;
                acc += w4.y * ob4[s4].y;
                acc += w4.z * ob4[s4].z;
                acc += w4.w * ob4[s4].w;
            }
            out[((b * kC + c) * kH + h) * kW + w0 + wp] =
                xbar + fac * (bo[c] + acc);
        }
    }
}

extern "C" void kernel_launch(void* const* d_in, const int* in_sizes, int n_in,
                              void* d_out, int out_size, void* d_ws, size_t ws_size,
                              hipStream_t stream) {
    const float* x      = (const float*)d_in[0];
    const float* Wk     = (const float*)d_in[1];
    const float* bk     = (const float*)d_in[2];
    const float* Wq     = (const float*)d_in[3];
    const float* bq     = (const float*)d_in[4];
    const float* Wv     = (const float*)d_in[5];
    const float* bv     = (const float*)d_in[6];
    const float* Wo     = (const float*)d_in[7];
    const float* bo     = (const float*)d_in[8];
    const float* factor = (const float*)d_in[9];
    float* out = (float*)d_out;

    dim3 grid(kB * kH * (kW / TW));  // 4096 blocks
    attn_fused<<<grid, NT, 0, stream>>>(x, Wk, bk, Wq, bq, Wv, bv, Wo, bo, factor, out);
}